// Round 6
// baseline (902.910 us; speedup 1.0000x reference)
//
#include <hip/hip_runtime.h>
#include <hip/hip_bf16.h>

#define NN 16384
#define DD 128
#define BM 32          // rows per block
#define BK 64          // k per pipeline stage
#define NT (NN / BK)   // 256 stages

typedef __attribute__((ext_vector_type(8))) short short8;
typedef __attribute__((ext_vector_type(4))) float f32x4;

__device__ __forceinline__ short f2bf(float f) {
  union { float f; unsigned u; } v; v.f = f;
  unsigned r = v.u + 0x7fffu + ((v.u >> 16) & 1u);   // RNE f32->bf16
  return (short)(r >> 16);
}
__device__ __forceinline__ float bf2f(short s) {
  union { unsigned u; float f; } v; v.u = ((unsigned)(unsigned short)s) << 16;
  return v.f;
}

#define WAITV(n) asm volatile("s_waitcnt vmcnt(" #n ")" ::: "memory")
#define BAR()    do { __builtin_amdgcn_s_barrier(); asm volatile("" ::: "memory"); } while (0)

// ---------------------------------------------------------------------------
// small GEMM: T = In @ W, written in MFMA B-fragment-major layout:
//   element (d, k):  kt=k>>5, dt=d>>4, lane=(d&15)|(((k>>3)&3)<<4), e=k&7
//   Tf[(((kt*8)+dt)*64 + lane)*8 + e]
// ---------------------------------------------------------------------------
template<int IN_BF16>
__global__ __launch_bounds__(256, 1)
void small_gemm(const void* __restrict__ In_, const float* __restrict__ W,
                short* __restrict__ Tf)
{
  __shared__ float sW[DD * DD];   // 64 KB
  const int tid = threadIdx.x;
  {
    const float4* W4 = (const float4*)W;
    float4* sW4 = (float4*)sW;
#pragma unroll
    for (int i = 0; i < 16; ++i) sW4[tid + 256 * i] = W4[tid + 256 * i];
  }
  __syncthreads();

  const int k0 = blockIdx.x * 16;
  const int kk = tid & 15;        // k-row within tile
  const int q  = tid >> 4;        // d-chunk 0..15 -> d = 8q..8q+7
  const long rowoff = (long)(k0 + kk) * DD;

  float acc[8] = {0.f, 0.f, 0.f, 0.f, 0.f, 0.f, 0.f, 0.f};
  if (IN_BF16) {
    const short8* In8 = (const short8*)((const short*)In_ + rowoff);
    for (int j8 = 0; j8 < 16; ++j8) {
      short8 a8 = In8[j8];
#pragma unroll
      for (int c = 0; c < 8; ++c) {
        float a = bf2f(a8[c]);
#pragma unroll
        for (int dd = 0; dd < 8; ++dd)
          acc[dd] += a * sW[(j8 * 8 + c) * DD + q * 8 + dd];
      }
    }
  } else {
    const float4* In4 = (const float4*)((const float*)In_ + rowoff);
    for (int j4 = 0; j4 < 32; ++j4) {
      float4 a4 = In4[j4];
      float av[4] = {a4.x, a4.y, a4.z, a4.w};
#pragma unroll
      for (int c = 0; c < 4; ++c)
#pragma unroll
        for (int dd = 0; dd < 8; ++dd)
          acc[dd] += av[c] * sW[(j4 * 4 + c) * DD + q * 8 + dd];
    }
  }

  const int k    = k0 + kk;
  const int kt   = k >> 5;
  const int ksub = (k >> 3) & 3;
  const int e    = k & 7;
#pragma unroll
  for (int dd = 0; dd < 8; ++dd) {
    const int d  = q * 8 + dd;
    const int dt = d >> 4;
    const int lf = (d & 15) | (ksub << 4);
    Tf[((((long)kt * 8) + dt) * 64 + lf) * 8 + e] = f2bf(acc[dd]);
  }
}

// ---------------------------------------------------------------------------
// aggregation: Out = relu(A @ T), T fragment-major bf16.
// BM=32 rows, grid 512 = 2 blocks/CU -> two INDEPENDENT barrier domains per
// CU: when one block waits on its counted vmcnt, the other keeps the HBM
// queue fed (fixes the zero-margin closed-loop convoy of 1-block/CU).
// Waves: w>>1 picks row half (16 rows), w&1 picks dt half (4 of 8).
// B: global_load_lds 4-buffer pipeline, distance 3, counted vmcnt, s_barrier.
// A: direct global->reg nontemporal, fp32->bf16 in reg.
// ---------------------------------------------------------------------------
template<int WRITE_BF16>
__global__ __launch_bounds__(256, 2)
void agg_kernel(const float* __restrict__ A, const short* __restrict__ Bf,
                void* __restrict__ out_)
{
  __shared__ __align__(16) short sB[4 * 8192];   // 4 bufs x 16 KB = 64 KB

  const int tid  = threadIdx.x;
  const int lane = tid & 63;
  const int w    = tid >> 6;                     // wave 0..3
  const int wr   = w >> 1;                       // row half
  const int wc   = w & 1;                        // dt half
  const long r0  = (long)blockIdx.x * BM + wr * 16;
  const int arow = lane & 15;
  const int kgrp = lane >> 4;

  const float* aptr = A + (r0 + arow) * (long)NN + kgrp * 8;
  const short* gsrc = Bf + w * 2048 + lane * 8;  // wave's quarter of 16KB tile
  short* lbase = &sB[0] + w * 2048;              // wave-uniform LDS dest base

  f32x4 acc[4];
#pragma unroll
  for (int j = 0; j < 4; ++j) acc[j] = (f32x4){0.f, 0.f, 0.f, 0.f};

  auto STAGE = [&](int buf, int t) {
    const short* g = gsrc + (long)t * 8192;
    short* l = lbase + buf * 8192;
#pragma unroll
    for (int i = 0; i < 4; ++i)
      __builtin_amdgcn_global_load_lds(
          (const __attribute__((address_space(1))) unsigned int*)(g + i * 512),
          (__attribute__((address_space(3))) unsigned int*)(l + i * 512),
          16, 0, 0);
  };
  auto ALOAD = [&](f32x4 (&ar)[4], int t) {
    const float* p = aptr + (long)t * BK;
    ar[0] = __builtin_nontemporal_load((const f32x4*)p);
    ar[1] = __builtin_nontemporal_load((const f32x4*)(p + 4));
    ar[2] = __builtin_nontemporal_load((const f32x4*)(p + 32));
    ar[3] = __builtin_nontemporal_load((const f32x4*)(p + 36));
  };
  auto COMPUTE = [&](int buf, f32x4 (&ar)[4]) {
    const short* lb = &sB[0] + buf * 8192 + lane * 8;
#pragma unroll
    for (int ks = 0; ks < 2; ++ks) {
      short8 af;
      af[0] = f2bf(ar[2 * ks].x); af[1] = f2bf(ar[2 * ks].y);
      af[2] = f2bf(ar[2 * ks].z); af[3] = f2bf(ar[2 * ks].w);
      af[4] = f2bf(ar[2 * ks + 1].x); af[5] = f2bf(ar[2 * ks + 1].y);
      af[6] = f2bf(ar[2 * ks + 1].z); af[7] = f2bf(ar[2 * ks + 1].w);
#pragma unroll
      for (int j = 0; j < 4; ++j) {
        const int dt = wc * 4 + j;
        short8 bf = *(const short8*)(lb + (ks * 8 + dt) * 512);
        acc[j] = __builtin_amdgcn_mfma_f32_16x16x32_bf16(af, bf, acc[j], 0, 0, 0);
      }
    }
  };

  f32x4 a0[4], a1[4], a2[4], a3[4];

  // prologue: stage tiles 0,1,2 (24 VMEM outstanding per wave)
  STAGE(0, 0); ALOAD(a0, 0);
  STAGE(1, 1); ALOAD(a1, 1);
  STAGE(2, 2); ALOAD(a2, 2);

  int t = 0;
  for (; t < NT - 4; t += 4) {
    WAITV(16); BAR(); STAGE(3, t + 3); ALOAD(a3, t + 3); COMPUTE(0, a0);
    WAITV(16); BAR(); STAGE(0, t + 4); ALOAD(a0, t + 4); COMPUTE(1, a1);
    WAITV(16); BAR(); STAGE(1, t + 5); ALOAD(a1, t + 5); COMPUTE(2, a2);
    WAITV(16); BAR(); STAGE(2, t + 6); ALOAD(a2, t + 6); COMPUTE(3, a3);
  }
  // t == NT-4: last stage is tile NT-1, then drain
  WAITV(16); BAR(); STAGE(3, t + 3); ALOAD(a3, t + 3); COMPUTE(0, a0);
  WAITV(16); BAR(); COMPUTE(1, a1);
  WAITV(8);  BAR(); COMPUTE(2, a2);
  WAITV(0);  BAR(); COMPUTE(3, a3);

  // epilogue: relu + store (C layout: row = kgrp*4 + r, col = dt*16 + arow)
#pragma unroll
  for (int j = 0; j < 4; ++j) {
#pragma unroll
    for (int r = 0; r < 4; ++r) {
      float v = acc[j][r];
      v = v > 0.f ? v : 0.f;
      const long row = r0 + kgrp * 4 + r;
      const int  col = (wc * 4 + j) * 16 + arow;
      if (WRITE_BF16)
        __builtin_nontemporal_store(f2bf(v), (short*)out_ + row * DD + col);
      else
        __builtin_nontemporal_store(v, (float*)out_ + row * DD + col);
    }
  }
}

// ---------------------------------------------------------------------------
extern "C" void kernel_launch(void* const* d_in, const int* in_sizes, int n_in,
                              void* d_out, int out_size, void* d_ws, size_t ws_size,
                              hipStream_t stream)
{
  const float* A  = (const float*)d_in[0];   // [16384][16384]
  const float* X  = (const float*)d_in[1];   // [16384][128]
  const float* W0 = (const float*)d_in[2];   // [128][128]
  const float* W1 = (const float*)d_in[3];   // [128][128]

  short* Tf = (short*)d_ws;                  // bf16 fragment-major T (4 MB)
  short* H1 = Tf + (size_t)DD * NN;          // bf16 [16384][128] post-relu H1

  // layer 0: T0 = X @ W0 ; H1 = relu(A @ T0)
  small_gemm<0><<<NN / 16, 256, 0, stream>>>(X, W0, Tf);
  agg_kernel<1><<<NN / BM, 256, 0, stream>>>(A, Tf, H1);
  // layer 1: T1 = H1 @ W1 ; out = relu(A @ T1)
  small_gemm<1><<<NN / 16, 256, 0, stream>>>(H1, W1, Tf);
  agg_kernel<0><<<NN / BM, 256, 0, stream>>>(A, Tf, d_out);
}

// Round 7
// 586.365 us; speedup vs baseline: 1.5398x; 1.5398x over previous
//
#include <hip/hip_runtime.h>
#include <hip/hip_bf16.h>

#define NN 16384
#define DD 128
#define BK 128         // k per pipeline stage (512 B per A-row per phase)
#define NT (NN / BK)   // 128 stages

typedef __attribute__((ext_vector_type(8))) short short8;
typedef __attribute__((ext_vector_type(4))) float f32x4;

__device__ __forceinline__ short f2bf(float f) {
  union { float f; unsigned u; } v; v.f = f;
  unsigned r = v.u + 0x7fffu + ((v.u >> 16) & 1u);   // RNE f32->bf16
  return (short)(r >> 16);
}
__device__ __forceinline__ float bf2f(short s) {
  union { unsigned u; float f; } v; v.u = ((unsigned)(unsigned short)s) << 16;
  return v.f;
}

#define WAITV(n) asm volatile("s_waitcnt vmcnt(" #n ")" ::: "memory")
#define BAR()    do { __builtin_amdgcn_s_barrier(); asm volatile("" ::: "memory"); } while (0)

// ---------------------------------------------------------------------------
// small GEMM: T = In @ W, written in MFMA B-fragment-major layout:
//   element (d, k):  kt=k>>5, dt=d>>4, lane=(d&15)|(((k>>3)&3)<<4), e=k&7
//   Tf[(((kt*8)+dt)*64 + lane)*8 + e]
// ---------------------------------------------------------------------------
template<int IN_BF16>
__global__ __launch_bounds__(256, 1)
void small_gemm(const void* __restrict__ In_, const float* __restrict__ W,
                short* __restrict__ Tf)
{
  __shared__ float sW[DD * DD];   // 64 KB
  const int tid = threadIdx.x;
  {
    const float4* W4 = (const float4*)W;
    float4* sW4 = (float4*)sW;
#pragma unroll
    for (int i = 0; i < 16; ++i) sW4[tid + 256 * i] = W4[tid + 256 * i];
  }
  __syncthreads();

  const int k0 = blockIdx.x * 16;
  const int kk = tid & 15;        // k-row within tile
  const int q  = tid >> 4;        // d-chunk 0..15 -> d = 8q..8q+7
  const long rowoff = (long)(k0 + kk) * DD;

  float acc[8] = {0.f, 0.f, 0.f, 0.f, 0.f, 0.f, 0.f, 0.f};
  if (IN_BF16) {
    const short8* In8 = (const short8*)((const short*)In_ + rowoff);
    for (int j8 = 0; j8 < 16; ++j8) {
      short8 a8 = In8[j8];
#pragma unroll
      for (int c = 0; c < 8; ++c) {
        float a = bf2f(a8[c]);
#pragma unroll
        for (int dd = 0; dd < 8; ++dd)
          acc[dd] += a * sW[(j8 * 8 + c) * DD + q * 8 + dd];
      }
    }
  } else {
    const float4* In4 = (const float4*)((const float*)In_ + rowoff);
    for (int j4 = 0; j4 < 32; ++j4) {
      float4 a4 = In4[j4];
      float av[4] = {a4.x, a4.y, a4.z, a4.w};
#pragma unroll
      for (int c = 0; c < 4; ++c)
#pragma unroll
        for (int dd = 0; dd < 8; ++dd)
          acc[dd] += av[c] * sW[(j4 * 4 + c) * DD + q * 8 + dd];
    }
  }

  const int k    = k0 + kk;
  const int kt   = k >> 5;
  const int ksub = (k >> 3) & 3;
  const int e    = k & 7;
#pragma unroll
  for (int dd = 0; dd < 8; ++dd) {
    const int d  = q * 8 + dd;
    const int dt = d >> 4;
    const int lf = (d & 15) | (ksub << 4);
    Tf[((((long)kt * 8) + dt) * 64 + lf) * 8 + e] = f2bf(acc[dd]);
  }
}

// ---------------------------------------------------------------------------
// aggregation: Out = relu(A @ T), T fragment-major bf16.
// Block = 64 rows (4 waves x 16 rows), grid 256 = 1 block/CU (R5 structure).
// BK=128: each A-row visited with 512 B per phase (DRAM-friendly), 128 phases.
// B: global_load_lds, 3-buffer LDS pipeline (96 KB), distance 2,
//    counted vmcnt (never 0 in main loop), raw s_barrier.
// A: direct global->reg nontemporal (keeps Tf L2/L3-hot), fp32->bf16 in reg.
// ---------------------------------------------------------------------------
template<int WRITE_BF16>
__global__ __launch_bounds__(256, 1)
void agg_kernel(const float* __restrict__ A, const short* __restrict__ Bf,
                void* __restrict__ out_)
{
  __shared__ __align__(16) short sB[3 * 16384];  // 3 bufs x 32 KB = 96 KB

  const int tid  = threadIdx.x;
  const int lane = tid & 63;
  const int w    = tid >> 6;                     // wave 0..3
  const long r0  = (long)blockIdx.x * 64 + w * 16;
  const int arow = lane & 15;
  const int kgrp = lane >> 4;

  const float* aptr = A + (r0 + arow) * (long)NN + kgrp * 8;
  const short* gsrc = Bf + w * 4096 + lane * 8;  // wave's quarter of 32KB tile
  short* lbase = &sB[0] + w * 4096;              // wave-uniform LDS dest base

  f32x4 acc[8];
#pragma unroll
  for (int dt = 0; dt < 8; ++dt) acc[dt] = (f32x4){0.f, 0.f, 0.f, 0.f};

  auto STAGE = [&](int buf, int t) {
    const short* g = gsrc + (long)t * 16384;
    short* l = lbase + buf * 16384;
#pragma unroll
    for (int i = 0; i < 8; ++i)
      __builtin_amdgcn_global_load_lds(
          (const __attribute__((address_space(1))) unsigned int*)(g + i * 512),
          (__attribute__((address_space(3))) unsigned int*)(l + i * 512),
          16, 0, 0);
  };
  auto ALOAD = [&](f32x4 (&ar)[8], int t) {
    const float* p = aptr + (long)t * BK;
#pragma unroll
    for (int s = 0; s < 4; ++s) {
      ar[2 * s]     = __builtin_nontemporal_load((const f32x4*)(p + s * 32));
      ar[2 * s + 1] = __builtin_nontemporal_load((const f32x4*)(p + s * 32 + 4));
    }
  };
  auto COMPUTE = [&](int buf, f32x4 (&ar)[8]) {
    const short* lb = &sB[0] + buf * 16384 + lane * 8;
#pragma unroll
    for (int s = 0; s < 4; ++s) {
      short8 af;
      af[0] = f2bf(ar[2 * s].x); af[1] = f2bf(ar[2 * s].y);
      af[2] = f2bf(ar[2 * s].z); af[3] = f2bf(ar[2 * s].w);
      af[4] = f2bf(ar[2 * s + 1].x); af[5] = f2bf(ar[2 * s + 1].y);
      af[6] = f2bf(ar[2 * s + 1].z); af[7] = f2bf(ar[2 * s + 1].w);
#pragma unroll
      for (int dt = 0; dt < 8; ++dt) {
        short8 bf = *(const short8*)(lb + (s * 8 + dt) * 512);
        acc[dt] = __builtin_amdgcn_mfma_f32_16x16x32_bf16(af, bf, acc[dt], 0, 0, 0);
      }
    }
  };

  f32x4 a0[8], a1[8], a2[8];

  // prologue: stage phases 0,1 (32 VMEM outstanding per wave)
  STAGE(0, 0); ALOAD(a0, 0);
  STAGE(1, 1); ALOAD(a1, 1);

  int t = 0;
  for (; t < NT - 4; t += 3) {
    WAITV(16); BAR(); STAGE(2, t + 2); ALOAD(a2, t + 2); COMPUTE(0, a0);
    WAITV(16); BAR(); STAGE(0, t + 3); ALOAD(a0, t + 3); COMPUTE(1, a1);
    WAITV(16); BAR(); STAGE(1, t + 4); ALOAD(a1, t + 4); COMPUTE(2, a2);
  }
  // t == 126: phases 126 (buf0), 127 (buf1) staged; drain
  WAITV(16); BAR(); COMPUTE(0, a0);
  WAITV(0);  BAR(); COMPUTE(1, a1);

  // epilogue: relu + store (C layout: row = kgrp*4 + r, col = dt*16 + arow)
#pragma unroll
  for (int dt = 0; dt < 8; ++dt) {
#pragma unroll
    for (int r = 0; r < 4; ++r) {
      float v = acc[dt][r];
      v = v > 0.f ? v : 0.f;
      const long row = r0 + kgrp * 4 + r;
      const int  col = dt * 16 + arow;
      if (WRITE_BF16)
        __builtin_nontemporal_store(f2bf(v), (short*)out_ + row * DD + col);
      else
        __builtin_nontemporal_store(v, (float*)out_ + row * DD + col);
    }
  }
}

// ---------------------------------------------------------------------------
extern "C" void kernel_launch(void* const* d_in, const int* in_sizes, int n_in,
                              void* d_out, int out_size, void* d_ws, size_t ws_size,
                              hipStream_t stream)
{
  const float* A  = (const float*)d_in[0];   // [16384][16384]
  const float* X  = (const float*)d_in[1];   // [16384][128]
  const float* W0 = (const float*)d_in[2];   // [128][128]
  const float* W1 = (const float*)d_in[3];   // [128][128]

  short* Tf = (short*)d_ws;                  // bf16 fragment-major T (4 MB)
  short* H1 = Tf + (size_t)DD * NN;          // bf16 [16384][128] post-relu H1

  // layer 0: T0 = X @ W0 ; H1 = relu(A @ T0)
  small_gemm<0><<<NN / 16, 256, 0, stream>>>(X, W0, Tf);
  agg_kernel<1><<<NN / 64, 256, 0, stream>>>(A, Tf, H1);
  // layer 1: T1 = H1 @ W1 ; out = relu(A @ T1)
  small_gemm<1><<<NN / 16, 256, 0, stream>>>(H1, W1, Tf);
  agg_kernel<0><<<NN / 64, 256, 0, stream>>>(A, Tf, d_out);
}

// Round 8
// 533.335 us; speedup vs baseline: 1.6930x; 1.0994x over previous
//
#include <hip/hip_runtime.h>
#include <hip/hip_bf16.h>

#define NN 16384
#define DD 128
#define BK 128         // k per pipeline stage (512 B per A-row per phase)
#define NT (NN / BK)   // 128 stages

typedef __attribute__((ext_vector_type(8))) short short8;
typedef __attribute__((ext_vector_type(4))) float f32x4;

__device__ __forceinline__ short f2bf(float f) {
  union { float f; unsigned u; } v; v.f = f;
  unsigned r = v.u + 0x7fffu + ((v.u >> 16) & 1u);   // RNE f32->bf16
  return (short)(r >> 16);
}
__device__ __forceinline__ float bf2f(short s) {
  union { unsigned u; float f; } v; v.u = ((unsigned)(unsigned short)s) << 16;
  return v.f;
}

#define WAITV(n) asm volatile("s_waitcnt vmcnt(" #n ")" ::: "memory")
#define BAR()    do { __builtin_amdgcn_s_barrier(); asm volatile("" ::: "memory"); } while (0)
#define SBAR()   __builtin_amdgcn_sched_barrier(0)

// ---------------------------------------------------------------------------
// small GEMM: T = In @ W, written in MFMA B-fragment-major layout:
//   element (d, k):  kt=k>>5, dt=d>>4, lane=(d&15)|(((k>>3)&3)<<4), e=k&7
//   Tf[(((kt*8)+dt)*64 + lane)*8 + e]
// ---------------------------------------------------------------------------
template<int IN_BF16>
__global__ __launch_bounds__(256, 1)
void small_gemm(const void* __restrict__ In_, const float* __restrict__ W,
                short* __restrict__ Tf)
{
  __shared__ float sW[DD * DD];   // 64 KB
  const int tid = threadIdx.x;
  {
    const float4* W4 = (const float4*)W;
    float4* sW4 = (float4*)sW;
#pragma unroll
    for (int i = 0; i < 16; ++i) sW4[tid + 256 * i] = W4[tid + 256 * i];
  }
  __syncthreads();

  const int k0 = blockIdx.x * 16;
  const int kk = tid & 15;        // k-row within tile
  const int q  = tid >> 4;        // d-chunk 0..15 -> d = 8q..8q+7
  const long rowoff = (long)(k0 + kk) * DD;

  float acc[8] = {0.f, 0.f, 0.f, 0.f, 0.f, 0.f, 0.f, 0.f};
  if (IN_BF16) {
    const short8* In8 = (const short8*)((const short*)In_ + rowoff);
    for (int j8 = 0; j8 < 16; ++j8) {
      short8 a8 = In8[j8];
#pragma unroll
      for (int c = 0; c < 8; ++c) {
        float a = bf2f(a8[c]);
#pragma unroll
        for (int dd = 0; dd < 8; ++dd)
          acc[dd] += a * sW[(j8 * 8 + c) * DD + q * 8 + dd];
      }
    }
  } else {
    const float4* In4 = (const float4*)((const float*)In_ + rowoff);
    for (int j4 = 0; j4 < 32; ++j4) {
      float4 a4 = In4[j4];
      float av[4] = {a4.x, a4.y, a4.z, a4.w};
#pragma unroll
      for (int c = 0; c < 4; ++c)
#pragma unroll
        for (int dd = 0; dd < 8; ++dd)
          acc[dd] += av[c] * sW[(j4 * 4 + c) * DD + q * 8 + dd];
    }
  }

  const int k    = k0 + kk;
  const int kt   = k >> 5;
  const int ksub = (k >> 3) & 3;
  const int e    = k & 7;
#pragma unroll
  for (int dd = 0; dd < 8; ++dd) {
    const int d  = q * 8 + dd;
    const int dt = d >> 4;
    const int lf = (d & 15) | (ksub << 4);
    Tf[((((long)kt * 8) + dt) * 64 + lf) * 8 + e] = f2bf(acc[dd]);
  }
}

// ---------------------------------------------------------------------------
// aggregation: Out = relu(A @ T), T fragment-major bf16.
// Block = 64 rows (4 waves x 16 rows), grid 256 = 1 block/CU.
// B: global_load_lds (normal caching -> Tf stays L2-resident), 3-buf LDS
//    pipeline (96 KB), distance 2, counted vmcnt (never 0), raw s_barrier.
// A: inline-asm global_load_dwordx4 sc1 nt -> BYPASSES L2 (A has no reuse;
//    keeps the 4 MB Tf resident in each XCD's 4 MB L2). fp32->bf16 in reg.
//    A loads are compiler-untracked => counted WAITV + sched_barrier(0)
//    provide the ordering guarantee (rule #18).
// ---------------------------------------------------------------------------
template<int WRITE_BF16>
__global__ __launch_bounds__(256, 1)
void agg_kernel(const float* __restrict__ A, const short* __restrict__ Bf,
                void* __restrict__ out_)
{
  __shared__ __align__(16) short sB[3 * 16384];  // 3 bufs x 32 KB = 96 KB

  const int tid  = threadIdx.x;
  const int lane = tid & 63;
  const int w    = tid >> 6;                     // wave 0..3
  const long r0  = (long)blockIdx.x * 64 + w * 16;
  const int arow = lane & 15;
  const int kgrp = lane >> 4;

  const float* aptr = A + (r0 + arow) * (long)NN + kgrp * 8;
  const short* gsrc = Bf + w * 4096 + lane * 8;  // wave's quarter of 32KB tile
  short* lbase = &sB[0] + w * 4096;              // wave-uniform LDS dest base

  f32x4 acc[8];
#pragma unroll
  for (int dt = 0; dt < 8; ++dt) acc[dt] = (f32x4){0.f, 0.f, 0.f, 0.f};

  auto STAGE = [&](int buf, int t) {
    const short* g = gsrc + (long)t * 16384;
    short* l = lbase + buf * 16384;
#pragma unroll
    for (int i = 0; i < 8; ++i)
      __builtin_amdgcn_global_load_lds(
          (const __attribute__((address_space(1))) unsigned int*)(g + i * 512),
          (__attribute__((address_space(3))) unsigned int*)(l + i * 512),
          16, 0, 0);
  };
  auto ALOAD = [&](f32x4 (&ar)[8], int t) {
    const float* p = aptr + (long)t * BK;
#pragma unroll
    for (int s = 0; s < 4; ++s) {
      asm volatile("global_load_dwordx4 %0, %1, off sc1 nt"
                   : "=v"(ar[2 * s]) : "v"(p + s * 32) : "memory");
      asm volatile("global_load_dwordx4 %0, %1, off sc1 nt"
                   : "=v"(ar[2 * s + 1]) : "v"(p + s * 32 + 4) : "memory");
    }
  };
  auto COMPUTE = [&](int buf, f32x4 (&ar)[8]) {
    const short* lb = &sB[0] + buf * 16384 + lane * 8;
#pragma unroll
    for (int s = 0; s < 4; ++s) {
      short8 af;
      af[0] = f2bf(ar[2 * s].x); af[1] = f2bf(ar[2 * s].y);
      af[2] = f2bf(ar[2 * s].z); af[3] = f2bf(ar[2 * s].w);
      af[4] = f2bf(ar[2 * s + 1].x); af[5] = f2bf(ar[2 * s + 1].y);
      af[6] = f2bf(ar[2 * s + 1].z); af[7] = f2bf(ar[2 * s + 1].w);
#pragma unroll
      for (int dt = 0; dt < 8; ++dt) {
        short8 bf = *(const short8*)(lb + (s * 8 + dt) * 512);
        acc[dt] = __builtin_amdgcn_mfma_f32_16x16x32_bf16(af, bf, acc[dt], 0, 0, 0);
      }
    }
  };

  f32x4 a0[8], a1[8], a2[8];

  // prologue: stage phases 0,1 (32 VMEM outstanding per wave)
  STAGE(0, 0); ALOAD(a0, 0);
  STAGE(1, 1); ALOAD(a1, 1);

  int t = 0;
  for (; t < NT - 4; t += 3) {
    WAITV(16); BAR(); SBAR(); STAGE(2, t + 2); ALOAD(a2, t + 2); COMPUTE(0, a0);
    WAITV(16); BAR(); SBAR(); STAGE(0, t + 3); ALOAD(a0, t + 3); COMPUTE(1, a1);
    WAITV(16); BAR(); SBAR(); STAGE(1, t + 4); ALOAD(a1, t + 4); COMPUTE(2, a2);
  }
  // t == 126: phases 126 (buf0), 127 (buf1) staged; drain
  WAITV(16); BAR(); SBAR(); COMPUTE(0, a0);
  WAITV(0);  BAR(); SBAR(); COMPUTE(1, a1);

  // epilogue: relu + store (C layout: row = kgrp*4 + r, col = dt*16 + arow)
#pragma unroll
  for (int dt = 0; dt < 8; ++dt) {
#pragma unroll
    for (int r = 0; r < 4; ++r) {
      float v = acc[dt][r];
      v = v > 0.f ? v : 0.f;
      const long row = r0 + kgrp * 4 + r;
      const int  col = dt * 16 + arow;
      if (WRITE_BF16)
        __builtin_nontemporal_store(f2bf(v), (short*)out_ + row * DD + col);
      else
        __builtin_nontemporal_store(v, (float*)out_ + row * DD + col);
    }
  }
}

// ---------------------------------------------------------------------------
extern "C" void kernel_launch(void* const* d_in, const int* in_sizes, int n_in,
                              void* d_out, int out_size, void* d_ws, size_t ws_size,
                              hipStream_t stream)
{
  const float* A  = (const float*)d_in[0];   // [16384][16384]
  const float* X  = (const float*)d_in[1];   // [16384][128]
  const float* W0 = (const float*)d_in[2];   // [128][128]
  const float* W1 = (const float*)d_in[3];   // [128][128]

  short* Tf = (short*)d_ws;                  // bf16 fragment-major T (4 MB)
  short* H1 = Tf + (size_t)DD * NN;          // bf16 [16384][128] post-relu H1

  // layer 0: T0 = X @ W0 ; H1 = relu(A @ T0)
  small_gemm<0><<<NN / 16, 256, 0, stream>>>(X, W0, Tf);
  agg_kernel<1><<<NN / 64, 256, 0, stream>>>(A, Tf, H1);
  // layer 1: T1 = H1 @ W1 ; out = relu(A @ T1)
  small_gemm<1><<<NN / 16, 256, 0, stream>>>(H1, W1, Tf);
  agg_kernel<0><<<NN / 64, 256, 0, stream>>>(A, Tf, d_out);
}

// Round 9
// 446.597 us; speedup vs baseline: 2.0218x; 1.1942x over previous
//
#include <hip/hip_runtime.h>
#include <hip/hip_bf16.h>

#define NN 16384
#define DD 128
#define BK 64          // k floats per pipeline stage
#define NT (NN / BK)   // 256 stages

typedef __attribute__((ext_vector_type(8))) short short8;
typedef __attribute__((ext_vector_type(4))) float f32x4;

__device__ __forceinline__ short f2bf(float f) {
  union { float f; unsigned u; } v; v.f = f;
  unsigned r = v.u + 0x7fffu + ((v.u >> 16) & 1u);   // RNE f32->bf16
  return (short)(r >> 16);
}
__device__ __forceinline__ float bf2f(short s) {
  union { unsigned u; float f; } v; v.u = ((unsigned)(unsigned short)s) << 16;
  return v.f;
}

#define WAITV(n) asm volatile("s_waitcnt vmcnt(" #n ")" ::: "memory")
#define BAR()    do { __builtin_amdgcn_s_barrier(); asm volatile("" ::: "memory"); } while (0)

// ---------------------------------------------------------------------------
// small GEMM: T = In @ W, written in MFMA B-fragment-major layout:
//   element (d, k):  kt=k>>5, dt=d>>4, lane=(d&15)|(((k>>3)&3)<<4), e=k&7
//   Tf[(((kt*8)+dt)*64 + lane)*8 + e]
// ---------------------------------------------------------------------------
template<int IN_BF16>
__global__ __launch_bounds__(256, 1)
void small_gemm(const void* __restrict__ In_, const float* __restrict__ W,
                short* __restrict__ Tf)
{
  __shared__ float sW[DD * DD];   // 64 KB
  const int tid = threadIdx.x;
  {
    const float4* W4 = (const float4*)W;
    float4* sW4 = (float4*)sW;
#pragma unroll
    for (int i = 0; i < 16; ++i) sW4[tid + 256 * i] = W4[tid + 256 * i];
  }
  __syncthreads();

  const int k0 = blockIdx.x * 16;
  const int kk = tid & 15;        // k-row within tile
  const int q  = tid >> 4;        // d-chunk 0..15 -> d = 8q..8q+7
  const long rowoff = (long)(k0 + kk) * DD;

  float acc[8] = {0.f, 0.f, 0.f, 0.f, 0.f, 0.f, 0.f, 0.f};
  if (IN_BF16) {
    const short8* In8 = (const short8*)((const short*)In_ + rowoff);
    for (int j8 = 0; j8 < 16; ++j8) {
      short8 a8 = In8[j8];
#pragma unroll
      for (int c = 0; c < 8; ++c) {
        float a = bf2f(a8[c]);
#pragma unroll
        for (int dd = 0; dd < 8; ++dd)
          acc[dd] += a * sW[(j8 * 8 + c) * DD + q * 8 + dd];
      }
    }
  } else {
    const float4* In4 = (const float4*)((const float*)In_ + rowoff);
    for (int j4 = 0; j4 < 32; ++j4) {
      float4 a4 = In4[j4];
      float av[4] = {a4.x, a4.y, a4.z, a4.w};
#pragma unroll
      for (int c = 0; c < 4; ++c)
#pragma unroll
        for (int dd = 0; dd < 8; ++dd)
          acc[dd] += av[c] * sW[(j4 * 4 + c) * DD + q * 8 + dd];
    }
  }

  const int k    = k0 + kk;
  const int kt   = k >> 5;
  const int ksub = (k >> 3) & 3;
  const int e    = k & 7;
#pragma unroll
  for (int dd = 0; dd < 8; ++dd) {
    const int d  = q * 8 + dd;
    const int dt = d >> 4;
    const int lf = (d & 15) | (ksub << 4);
    Tf[((((long)kt * 8) + dt) * 64 + lf) * 8 + e] = f2bf(acc[dd]);
  }
}

// ---------------------------------------------------------------------------
// aggregation: Out = relu(A @ T), T fragment-major bf16.
// Block = 64 rows (4 waves x 16 rows), grid 256 = 1 block/CU.
// BOTH operands staged via global_load_lds (lane-contiguous 1 KB per
// instruction -> full-line HBM bursts; fixes the 16-row/16B-granule scatter
// of direct A-fragment loads). A staged fp32 with XOR-swizzle (row&7)<<4
// (pre-swizzled global source + swizzled ds_read, rule #21), aux=SC1|NT so
// the A stream bypasses L2 and Tf stays L2-resident (R8 win). B aux=0.
// 4-buffer pipeline (128 KB LDS), distance 3, counted vmcnt (8 VMEM/phase).
// ---------------------------------------------------------------------------
template<int WRITE_BF16>
__global__ __launch_bounds__(256, 1)
void agg_kernel(const float* __restrict__ A, const short* __restrict__ Bf,
                void* __restrict__ out_)
{
  __shared__ __align__(16) char sMem[131072];    // A: 4x16KB | B: 4x16KB
  char* sA = sMem;
  char* sB = sMem + 65536;

  const int tid  = threadIdx.x;
  const int lane = tid & 63;
  const int w    = tid >> 6;                     // wave 0..3
  const long rb  = (long)blockIdx.x * 64;        // block row base
  const int arow = lane & 15;
  const int kgrp = lane >> 4;

  // ---- A staging geometry (per-lane, per-instr i) ----
  // lds byte (within tile) o = w*4096 + i*1024 + lane*16
  // row = o>>8, col_byte = o&255, source col pre-swizzled by (row&7)<<4
  int rowi[4], colfi[4];
#pragma unroll
  for (int i = 0; i < 4; ++i) {
    const int o  = w * 4096 + i * 1024 + lane * 16;
    const int rr = o >> 8;
    const int cb = (o & 255) ^ ((rr & 7) << 4);
    rowi[i] = rr;            // 0..63
    colfi[i] = cb >> 2;      // float offset 0..63
  }
  const short* gsrcB = Bf + w * 2048 + lane * 8;
  char* ldsAu = sA + w * 4096;                   // wave-uniform dests
  char* ldsBu = sB + w * 4096;

  f32x4 acc[8];
#pragma unroll
  for (int dt = 0; dt < 8; ++dt) acc[dt] = (f32x4){0.f, 0.f, 0.f, 0.f};

  auto STAGE = [&](int buf, int t) {
    // A: fp32, pre-swizzled source, L2-bypass (SC1|NT = 0x12)
#pragma unroll
    for (int i = 0; i < 4; ++i) {
      const float* g = A + (rb + rowi[i]) * (long)NN + t * BK + colfi[i];
      __builtin_amdgcn_global_load_lds(
          (const __attribute__((address_space(1))) unsigned int*)g,
          (__attribute__((address_space(3))) unsigned int*)(ldsAu + buf * 16384 + i * 1024),
          16, 0, 0x12);
    }
    // B: bf16 frag-major, normal caching (L2-resident)
    const short* g = gsrcB + (long)t * 8192;
#pragma unroll
    for (int i = 0; i < 4; ++i)
      __builtin_amdgcn_global_load_lds(
          (const __attribute__((address_space(1))) unsigned int*)(g + i * 512),
          (__attribute__((address_space(3))) unsigned int*)(ldsBu + buf * 16384 + i * 1024),
          16, 0, 0);
  };

  auto COMPUTE = [&](int buf) {
    const char* la = sA + buf * 16384;
    const char* lb = sB + buf * 16384 + lane * 16;
    const int row = w * 16 + arow;
    const int sw  = (arow & 7) << 4;
#pragma unroll
    for (int ks = 0; ks < 2; ++ks) {
      f32x4 a0 = *(const f32x4*)(la + row * 256 + ((ks * 128 + kgrp * 32) ^ sw));
      f32x4 a1 = *(const f32x4*)(la + row * 256 + ((ks * 128 + kgrp * 32 + 16) ^ sw));
      short8 af;
      af[0] = f2bf(a0.x); af[1] = f2bf(a0.y); af[2] = f2bf(a0.z); af[3] = f2bf(a0.w);
      af[4] = f2bf(a1.x); af[5] = f2bf(a1.y); af[6] = f2bf(a1.z); af[7] = f2bf(a1.w);
#pragma unroll
      for (int dt = 0; dt < 8; ++dt) {
        short8 bf = *(const short8*)(lb + (ks * 8 + dt) * 1024);
        acc[dt] = __builtin_amdgcn_mfma_f32_16x16x32_bf16(af, bf, acc[dt], 0, 0, 0);
      }
    }
  };

  // prologue: stage tiles 0,1,2 (24 VMEM outstanding per wave)
  STAGE(0, 0); STAGE(1, 1); STAGE(2, 2);

  int t = 0;
  for (; t < NT - 4; t += 4) {
    WAITV(16); BAR(); STAGE(3, t + 3); COMPUTE(0);
    WAITV(16); BAR(); STAGE(0, t + 4); COMPUTE(1);
    WAITV(16); BAR(); STAGE(1, t + 5); COMPUTE(2);
    WAITV(16); BAR(); STAGE(2, t + 6); COMPUTE(3);
  }
  // t == NT-4: stage last tile NT-1, then drain
  WAITV(16); BAR(); STAGE(3, t + 3); COMPUTE(0);
  WAITV(16); BAR(); COMPUTE(1);
  WAITV(8);  BAR(); COMPUTE(2);
  WAITV(0);  BAR(); COMPUTE(3);

  // epilogue: relu + store (C layout: row = kgrp*4 + r, col = dt*16 + arow)
#pragma unroll
  for (int dt = 0; dt < 8; ++dt) {
#pragma unroll
    for (int r = 0; r < 4; ++r) {
      float v = acc[dt][r];
      v = v > 0.f ? v : 0.f;
      const long row = rb + w * 16 + kgrp * 4 + r;
      const int  col = dt * 16 + arow;
      if (WRITE_BF16)
        __builtin_nontemporal_store(f2bf(v), (short*)out_ + row * DD + col);
      else
        __builtin_nontemporal_store(v, (float*)out_ + row * DD + col);
    }
  }
}

// ---------------------------------------------------------------------------
extern "C" void kernel_launch(void* const* d_in, const int* in_sizes, int n_in,
                              void* d_out, int out_size, void* d_ws, size_t ws_size,
                              hipStream_t stream)
{
  const float* A  = (const float*)d_in[0];   // [16384][16384]
  const float* X  = (const float*)d_in[1];   // [16384][128]
  const float* W0 = (const float*)d_in[2];   // [128][128]
  const float* W1 = (const float*)d_in[3];   // [128][128]

  short* Tf = (short*)d_ws;                  // bf16 fragment-major T (4 MB)
  short* H1 = Tf + (size_t)DD * NN;          // bf16 [16384][128] post-relu H1

  // layer 0: T0 = X @ W0 ; H1 = relu(A @ T0)
  small_gemm<0><<<NN / 16, 256, 0, stream>>>(X, W0, Tf);
  agg_kernel<1><<<NN / 64, 256, 0, stream>>>(A, Tf, H1);
  // layer 1: T1 = H1 @ W1 ; out = relu(A @ T1)
  small_gemm<1><<<NN / 16, 256, 0, stream>>>(H1, W1, Tf);
  agg_kernel<0><<<NN / 64, 256, 0, stream>>>(A, Tf, d_out);
}